// Round 1
// baseline (200.187 us; speedup 1.0000x reference)
//
#include <hip/hip_runtime.h>
#include <hip/hip_bf16.h>

#define B_ 2
#define H_ 16
#define T_ 2048
#define D_ 64
#define TQ 16          // q rows per wave
#define NW 4           // waves per block
#define QBLK (TQ*NW)   // 64 q rows per block
#define KVB 32         // kv tile
#define PSTR 36        // padded LDS row stride (floats) for P

typedef __attribute__((ext_vector_type(8))) short bf16x8;
typedef __attribute__((ext_vector_type(4))) float f32x4;

__device__ __forceinline__ short f2bf(float x) {
    __hip_bfloat16 h = __float2bfloat16(x);
    return __builtin_bit_cast(short, h);
}

__global__ __launch_bounds__(NW*64) void attn_fwd(
    const float* __restrict__ q, const float* __restrict__ k,
    const float* __restrict__ v, const float* __restrict__ fp,
    const float* __restrict__ vmask, const float* __restrict__ hmask,
    float* __restrict__ out)
{
    const int nQB = T_/QBLK;
    const int bh = blockIdx.x / nQB;
    const int qb = blockIdx.x % nQB;
    const int b  = bh / H_;
    const int lane = threadIdx.x & 63;
    const int wid  = threadIdx.x >> 6;
    const int g = lane >> 4, c = lane & 15;

    const float* qb_p = q + (size_t)bh*T_*D_;
    const float* kb_p = k + (size_t)bh*D_*T_;   // [D][T]
    const float* vb_p = v + (size_t)bh*T_*D_;
    float*       ob_p = out + (size_t)bh*T_*D_;
    const float* vm_p = vmask + (size_t)b*T_;
    const float* hm_p = hmask + (size_t)b*T_;

    const float invf = 1.0f / fp[0];

    const int i0 = qb*QBLK + wid*TQ;

    // Q A-fragments: A[row=c][kk = ck*32 + g*8 + e], hoisted for whole kernel
    bf16x8 qa[2];
    #pragma unroll
    for (int ck = 0; ck < 2; ++ck) {
        const float* src = qb_p + (size_t)(i0 + c)*D_ + ck*32 + g*8;
        float4 x0 = *reinterpret_cast<const float4*>(src);
        float4 x1 = *reinterpret_cast<const float4*>(src+4);
        bf16x8 a;
        a[0]=f2bf(x0.x); a[1]=f2bf(x0.y); a[2]=f2bf(x0.z); a[3]=f2bf(x0.w);
        a[4]=f2bf(x1.x); a[5]=f2bf(x1.y); a[6]=f2bf(x1.z); a[7]=f2bf(x1.w);
        qa[ck]=a;
    }

    // row (query) mask, hoisted; rows owned by this lane: i0 + g*4 + r
    float hm[4];
    #pragma unroll
    for (int r=0;r<4;++r) hm[r] = hm_p[i0 + g*4 + r];

    float m_run[4], l_run[4];
    f32x4 oacc[4];
    #pragma unroll
    for (int r=0;r<4;++r){ m_run[r] = -__builtin_inff(); l_run[r] = 0.f; }
    #pragma unroll
    for (int dt=0;dt<4;++dt) oacc[dt] = (f32x4){0.f,0.f,0.f,0.f};

    __shared__ float Pl[NW][TQ][PSTR];
    float (*Pw)[PSTR] = Pl[wid];

    const int ntile = ((i0 + TQ - 1) >> 5) + 1;   // causal: tiles with j0 <= i_max

    for (int t = 0; t < ntile; ++t) {
        const int j0 = t*KVB;

        // ---- S = Q K / f  (two 16-col tiles) ----
        f32x4 sacc[2] = {{0.f,0.f,0.f,0.f},{0.f,0.f,0.f,0.f}};
        #pragma unroll
        for (int jt=0;jt<2;++jt) {
            #pragma unroll
            for (int ck=0;ck<2;++ck) {
                // B frag: B[kk=g*8+e][col=c] = k[d = ck*32+g*8+e][j0 + jt*16 + c]
                bf16x8 bfrag;
                const float* ks = kb_p + (size_t)(ck*32 + g*8)*T_ + j0 + jt*16 + c;
                #pragma unroll
                for (int e=0;e<8;++e) bfrag[e] = f2bf(ks[(size_t)e*T_]);
                sacc[jt] = __builtin_amdgcn_mfma_f32_16x16x32_bf16(qa[ck], bfrag, sacc[jt], 0,0,0);
            }
        }

        // ---- masks + online softmax ----
        float vmv[2];
        vmv[0] = vm_p[j0 + c];
        vmv[1] = vm_p[j0 + 16 + c];

        float p[2][4];
        float fac[4];
        #pragma unroll
        for (int r=0;r<4;++r) {
            const int irow = i0 + g*4 + r;
            float best = -__builtin_inff();
            #pragma unroll
            for (int jt=0;jt<2;++jt) {
                const int j = j0 + jt*16 + c;
                float sv = sacc[jt][r] * invf;
                const bool padv = (vmv[jt] != 0.f) && (hm[r] != 0.f);
                sv = padv ? sv : 1e-10f;              // masked_fill(s==0, 1e-10)
                sv = (j > irow) ? -__builtin_inff() : sv;  // causal
                p[jt][r] = sv;
                best = fmaxf(best, sv);
            }
            best = fmaxf(best, __shfl_xor(best, 1));
            best = fmaxf(best, __shfl_xor(best, 2));
            best = fmaxf(best, __shfl_xor(best, 4));
            best = fmaxf(best, __shfl_xor(best, 8));

            const float mn = fmaxf(m_run[r], best);
            fac[r] = __expf(m_run[r] - mn);
            m_run[r] = mn;
            float rs = 0.f;
            #pragma unroll
            for (int jt=0;jt<2;++jt) {
                const float e = __expf(p[jt][r] - mn);
                p[jt][r] = e;
                rs += e;
            }
            rs += __shfl_xor(rs, 1);
            rs += __shfl_xor(rs, 2);
            rs += __shfl_xor(rs, 4);
            rs += __shfl_xor(rs, 8);
            l_run[r] = l_run[r]*fac[r] + rs;
        }

        #pragma unroll
        for (int dt=0;dt<4;++dt)
            #pragma unroll
            for (int r=0;r<4;++r)
                oacc[dt][r] *= fac[r];

        // ---- P: C-layout -> A-layout via wave-private LDS ----
        #pragma unroll
        for (int r=0;r<4;++r)
            #pragma unroll
            for (int jt=0;jt<2;++jt)
                Pw[g*4+r][jt*16+c] = p[jt][r];
        asm volatile("s_waitcnt lgkmcnt(0)" ::: "memory");

        const float* ps = &Pw[c][g*8];
        float4 p0 = *reinterpret_cast<const float4*>(ps);
        float4 p1 = *reinterpret_cast<const float4*>(ps+4);
        bf16x8 pf;
        pf[0]=f2bf(p0.x); pf[1]=f2bf(p0.y); pf[2]=f2bf(p0.z); pf[3]=f2bf(p0.w);
        pf[4]=f2bf(p1.x); pf[5]=f2bf(p1.y); pf[6]=f2bf(p1.z); pf[7]=f2bf(p1.w);

        // ---- O += P V ----
        #pragma unroll
        for (int dt=0;dt<4;++dt) {
            bf16x8 vf;
            const float* vs = vb_p + (size_t)(j0 + g*8)*D_ + dt*16 + c;
            #pragma unroll
            for (int e=0;e<8;++e) vf[e] = f2bf(vs[(size_t)e*D_]);
            oacc[dt] = __builtin_amdgcn_mfma_f32_16x16x32_bf16(pf, vf, oacc[dt], 0,0,0);
        }
    }

    // ---- epilogue: O / l ----
    #pragma unroll
    for (int r=0;r<4;++r) {
        const float rinv = 1.0f / l_run[r];
        const int row = i0 + g*4 + r;
        #pragma unroll
        for (int dt=0;dt<4;++dt)
            ob_p[(size_t)row*D_ + dt*16 + c] = oacc[dt][r] * rinv;
    }
}

extern "C" void kernel_launch(void* const* d_in, const int* in_sizes, int n_in,
                              void* d_out, int out_size, void* d_ws, size_t ws_size,
                              hipStream_t stream) {
    const float* q  = (const float*)d_in[0];
    const float* k  = (const float*)d_in[1];
    const float* v  = (const float*)d_in[2];
    const float* f  = (const float*)d_in[3];
    const float* vm = (const float*)d_in[4];
    const float* hm = (const float*)d_in[5];
    float* out = (float*)d_out;

    dim3 grid(B_*H_*(T_/QBLK));
    dim3 block(NW*64);
    hipLaunchKernelGGL(attn_fwd, grid, block, 0, stream, q, k, v, f, vm, hm, out);
}

// Round 2
// 157.972 us; speedup vs baseline: 1.2672x; 1.2672x over previous
//
#include <hip/hip_runtime.h>
#include <hip/hip_bf16.h>

#define B_ 2
#define H_ 16
#define T_ 2048
#define D_ 64
#define BH (B_*H_)
#define TQ 16          // q rows per wave (1 wave per block)
#define PSTR 68        // padded LDS row stride (floats) for P

typedef __attribute__((ext_vector_type(8))) short bf16x8;
typedef __attribute__((ext_vector_type(4))) float f32x4;

__device__ __forceinline__ short f2bf(float x) {
    __hip_bfloat16 h = __float2bfloat16(x);
    return __builtin_bit_cast(short, h);
}
__device__ __forceinline__ ushort f2bu(float x) {
    __hip_bfloat16 h = __float2bfloat16(x);
    return __builtin_bit_cast(ushort, h);
}

// transpose f32 [M][N] -> bf16 [N][M] per-bh slab. grid(BH, M/64, N/64), block 256.
__global__ __launch_bounds__(256) void tr_bf16(const float* __restrict__ src,
                                               ushort* __restrict__ dst,
                                               int M, int N) {
    __shared__ ushort tl[64][65];
    const int bh = blockIdx.x;
    const int i0 = blockIdx.y * 64, j0 = blockIdx.z * 64;
    const float* s = src + (size_t)bh * M * N;
    ushort*      d = dst + (size_t)bh * M * N;
    const int tid = threadIdx.x;
    const int rr = tid >> 4, c4 = (tid & 15) * 4;
    #pragma unroll
    for (int p = 0; p < 4; ++p) {
        int a = p * 16 + rr;
        float4 x = *reinterpret_cast<const float4*>(&s[(size_t)(i0 + a) * N + j0 + c4]);
        tl[c4 + 0][a] = f2bu(x.x); tl[c4 + 1][a] = f2bu(x.y);
        tl[c4 + 2][a] = f2bu(x.z); tl[c4 + 3][a] = f2bu(x.w);
    }
    __syncthreads();
    #pragma unroll
    for (int p = 0; p < 4; ++p) {
        int b = p * 16 + rr;
        ushort4 u;
        u.x = tl[b][c4]; u.y = tl[b][c4 + 1]; u.z = tl[b][c4 + 2]; u.w = tl[b][c4 + 3];
        *reinterpret_cast<ushort4*>(&d[(size_t)(j0 + b) * M + i0 + c4]) = u;
    }
}

// PREP=1: read bf16 KT [t][d], VT [d][t] via 16B loads. PREP=0: strided f32 fallback.
template <int PREP>
__global__ __launch_bounds__(64, 4) void attn_fwd(
    const float* __restrict__ q, const float* __restrict__ k,
    const float* __restrict__ v, const float* __restrict__ fp,
    const float* __restrict__ vmask, const float* __restrict__ hmask,
    const ushort* __restrict__ KT, const ushort* __restrict__ VT,
    float* __restrict__ out)
{
    const int nQW = T_ / TQ;                 // 128
    const int bh = blockIdx.x & (BH - 1);
    const int qw = (nQW - 1) - (blockIdx.x >> 5);   // heavy-first
    const int b  = bh / H_;
    const int lane = threadIdx.x & 63;
    const int g = lane >> 4, c = lane & 15;

    const float* qb_p = q + (size_t)bh * T_ * D_;
    const float* kb_p = k + (size_t)bh * D_ * T_;   // [D][T]
    const float* vb_p = v + (size_t)bh * T_ * D_;
    const ushort* KTb = KT + (size_t)bh * T_ * D_;  // [T][D]
    const ushort* VTb = VT + (size_t)bh * T_ * D_;  // [D][T]
    float*       ob_p = out + (size_t)bh * T_ * D_;
    const float* vm_p = vmask + (size_t)b * T_;
    const float* hm_p = hmask + (size_t)b * T_;

    const float invf = 1.0f / fp[0];
    const int i0 = qw * TQ;

    // Q A-fragments (hoisted): A[row=c][kk=ck*32+g*8+e]
    bf16x8 qa[2];
    #pragma unroll
    for (int ck = 0; ck < 2; ++ck) {
        const float* src = qb_p + (size_t)(i0 + c) * D_ + ck * 32 + g * 8;
        float4 x0 = *reinterpret_cast<const float4*>(src);
        float4 x1 = *reinterpret_cast<const float4*>(src + 4);
        bf16x8 a;
        a[0]=f2bf(x0.x); a[1]=f2bf(x0.y); a[2]=f2bf(x0.z); a[3]=f2bf(x0.w);
        a[4]=f2bf(x1.x); a[5]=f2bf(x1.y); a[6]=f2bf(x1.z); a[7]=f2bf(x1.w);
        qa[ck] = a;
    }

    float hm[4];
    #pragma unroll
    for (int r = 0; r < 4; ++r) hm[r] = hm_p[i0 + g * 4 + r];

    float m_run[4], l_run[4];
    f32x4 oacc[4];
    #pragma unroll
    for (int r = 0; r < 4; ++r) { m_run[r] = -__builtin_inff(); l_run[r] = 0.f; }
    #pragma unroll
    for (int dt = 0; dt < 4; ++dt) oacc[dt] = (f32x4){0.f, 0.f, 0.f, 0.f};

    __shared__ float Pw[TQ][PSTR];   // single wave per block

    const int nstep = ((i0 + TQ - 1) >> 6) + 1;   // KV tiles of 64, causal bound

    for (int t = 0; t < nstep; ++t) {
        const int j0 = t * 64;

        // ---- S = Q K^T / f over 64 keys (4 col-tiles of 16) ----
        f32x4 sacc[4];
        #pragma unroll
        for (int jt = 0; jt < 4; ++jt) sacc[jt] = (f32x4){0.f, 0.f, 0.f, 0.f};

        if constexpr (PREP) {
            #pragma unroll
            for (int jt = 0; jt < 4; ++jt) {
                const ushort* kp = KTb + (size_t)(j0 + jt * 16 + c) * D_ + g * 8;
                bf16x8 kb0 = *reinterpret_cast<const bf16x8*>(kp);
                bf16x8 kb1 = *reinterpret_cast<const bf16x8*>(kp + 32);
                sacc[jt] = __builtin_amdgcn_mfma_f32_16x16x32_bf16(qa[0], kb0, sacc[jt], 0,0,0);
                sacc[jt] = __builtin_amdgcn_mfma_f32_16x16x32_bf16(qa[1], kb1, sacc[jt], 0,0,0);
            }
        } else {
            #pragma unroll
            for (int jt = 0; jt < 4; ++jt) {
                #pragma unroll
                for (int ck = 0; ck < 2; ++ck) {
                    bf16x8 bfrag;
                    const float* ks = kb_p + (size_t)(ck * 32 + g * 8) * T_ + j0 + jt * 16 + c;
                    #pragma unroll
                    for (int e = 0; e < 8; ++e) bfrag[e] = f2bf(ks[(size_t)e * T_]);
                    sacc[jt] = __builtin_amdgcn_mfma_f32_16x16x32_bf16(qa[ck], bfrag, sacc[jt], 0,0,0);
                }
            }
        }

        // ---- masks + online softmax over this 64-key tile ----
        float vmv[4];
        #pragma unroll
        for (int jt = 0; jt < 4; ++jt) vmv[jt] = vm_p[j0 + jt * 16 + c];

        float p[4][4];   // [jt][r]
        float fac[4];
        #pragma unroll
        for (int r = 0; r < 4; ++r) {
            const int irow = i0 + g * 4 + r;
            float best = -__builtin_inff();
            #pragma unroll
            for (int jt = 0; jt < 4; ++jt) {
                const int j = j0 + jt * 16 + c;
                float sv = sacc[jt][r] * invf;
                const bool padv = (vmv[jt] != 0.f) && (hm[r] != 0.f);
                sv = padv ? sv : 1e-10f;                   // masked_fill(s==0, 1e-10)
                sv = (j > irow) ? -__builtin_inff() : sv;  // causal
                p[jt][r] = sv;
                best = fmaxf(best, sv);
            }
            best = fmaxf(best, __shfl_xor(best, 1));
            best = fmaxf(best, __shfl_xor(best, 2));
            best = fmaxf(best, __shfl_xor(best, 4));
            best = fmaxf(best, __shfl_xor(best, 8));

            const float mn = fmaxf(m_run[r], best);
            fac[r] = __expf(m_run[r] - mn);
            m_run[r] = mn;
            float rs = 0.f;
            #pragma unroll
            for (int jt = 0; jt < 4; ++jt) {
                const float e = __expf(p[jt][r] - mn);
                p[jt][r] = e;
                rs += e;
            }
            rs += __shfl_xor(rs, 1);
            rs += __shfl_xor(rs, 2);
            rs += __shfl_xor(rs, 4);
            rs += __shfl_xor(rs, 8);
            l_run[r] = l_run[r] * fac[r] + rs;
        }

        #pragma unroll
        for (int dt = 0; dt < 4; ++dt)
            #pragma unroll
            for (int r = 0; r < 4; ++r)
                oacc[dt][r] *= fac[r];

        // ---- P: C-layout -> A-layout via wave-private LDS ----
        #pragma unroll
        for (int r = 0; r < 4; ++r)
            #pragma unroll
            for (int jt = 0; jt < 4; ++jt)
                Pw[g * 4 + r][jt * 16 + c] = p[jt][r];
        asm volatile("s_waitcnt lgkmcnt(0)" ::: "memory");
        __builtin_amdgcn_sched_barrier(0);

        bf16x8 pf[2];
        #pragma unroll
        for (int kc = 0; kc < 2; ++kc) {
            const float* ps = &Pw[c][kc * 32 + g * 8];
            float4 p0 = *reinterpret_cast<const float4*>(ps);
            float4 p1 = *reinterpret_cast<const float4*>(ps + 4);
            bf16x8 pfv;
            pfv[0]=f2bf(p0.x); pfv[1]=f2bf(p0.y); pfv[2]=f2bf(p0.z); pfv[3]=f2bf(p0.w);
            pfv[4]=f2bf(p1.x); pfv[5]=f2bf(p1.y); pfv[6]=f2bf(p1.z); pfv[7]=f2bf(p1.w);
            pf[kc] = pfv;
        }

        // ---- O += P V ----
        if constexpr (PREP) {
            #pragma unroll
            for (int dt = 0; dt < 4; ++dt) {
                const ushort* vp = VTb + (size_t)(dt * 16 + c) * T_ + j0 + g * 8;
                bf16x8 v0 = *reinterpret_cast<const bf16x8*>(vp);
                bf16x8 v1 = *reinterpret_cast<const bf16x8*>(vp + 32);
                oacc[dt] = __builtin_amdgcn_mfma_f32_16x16x32_bf16(pf[0], v0, oacc[dt], 0,0,0);
                oacc[dt] = __builtin_amdgcn_mfma_f32_16x16x32_bf16(pf[1], v1, oacc[dt], 0,0,0);
            }
        } else {
            #pragma unroll
            for (int dt = 0; dt < 4; ++dt) {
                #pragma unroll
                for (int kc = 0; kc < 2; ++kc) {
                    bf16x8 vf;
                    const float* vs = vb_p + (size_t)(j0 + kc * 32 + g * 8) * D_ + dt * 16 + c;
                    #pragma unroll
                    for (int e = 0; e < 8; ++e) vf[e] = f2bf(vs[(size_t)e * D_]);
                    oacc[dt] = __builtin_amdgcn_mfma_f32_16x16x32_bf16(pf[kc], vf, oacc[dt], 0,0,0);
                }
            }
        }
    }

    // ---- epilogue: O / l ----
    #pragma unroll
    for (int r = 0; r < 4; ++r) {
        const float rinv = 1.0f / l_run[r];
        const int row = i0 + g * 4 + r;
        #pragma unroll
        for (int dt = 0; dt < 4; ++dt)
            ob_p[(size_t)row * D_ + dt * 16 + c] = oacc[dt][r] * rinv;
    }
}

extern "C" void kernel_launch(void* const* d_in, const int* in_sizes, int n_in,
                              void* d_out, int out_size, void* d_ws, size_t ws_size,
                              hipStream_t stream) {
    const float* q  = (const float*)d_in[0];
    const float* k  = (const float*)d_in[1];
    const float* v  = (const float*)d_in[2];
    const float* f  = (const float*)d_in[3];
    const float* vm = (const float*)d_in[4];
    const float* hm = (const float*)d_in[5];
    float* out = (float*)d_out;

    const size_t slab = (size_t)BH * T_ * D_;          // elements per tensor
    const size_t need = 2 * slab * sizeof(ushort);     // KT + VT, bf16
    ushort* KT = (ushort*)d_ws;
    ushort* VT = KT + slab;
    const bool prep = (ws_size >= need);

    if (prep) {
        // k: f32 [D][T] -> KT bf16 [T][D]
        hipLaunchKernelGGL(tr_bf16, dim3(BH, 1, T_ / 64), dim3(256), 0, stream, k, KT, D_, T_);
        // v: f32 [T][D] -> VT bf16 [D][T]
        hipLaunchKernelGGL(tr_bf16, dim3(BH, T_ / 64, 1), dim3(256), 0, stream, v, VT, T_, D_);
    }

    dim3 grid(BH * (T_ / TQ));   // 4096 one-wave blocks, heavy-first mapping inside
    dim3 block(64);
    if (prep)
        hipLaunchKernelGGL((attn_fwd<1>), grid, block, 0, stream, q, k, v, f, vm, hm, KT, VT, out);
    else
        hipLaunchKernelGGL((attn_fwd<0>), grid, block, 0, stream, q, k, v, f, vm, hm, KT, VT, out);
}

// Round 3
// 89.428 us; speedup vs baseline: 2.2385x; 1.7665x over previous
//
#include <hip/hip_runtime.h>
#include <hip/hip_bf16.h>

#define B_ 2
#define H_ 16
#define T_ 2048
#define D_ 64
#define BH (B_*H_)
#define QB 32

typedef __attribute__((ext_vector_type(8))) short bf16x8;
typedef __attribute__((ext_vector_type(16))) float f32x16;
typedef __attribute__((ext_vector_type(4))) unsigned int u32x4;
typedef unsigned int u32;

__device__ __forceinline__ ushort f2bu(float x){
    __hip_bfloat16 h = __float2bfloat16(x);
    return __builtin_bit_cast(ushort, h);
}
__device__ __forceinline__ u32 cvtpk(float a, float b){
    u32 r; asm("v_cvt_pk_bf16_f32 %0, %1, %2" : "=v"(r) : "v"(a), "v"(b)); return r;
}

// transpose f32 [M][N] -> bf16 [N][M] per-bh slab. Optional vm: zero dst row
// (key t = j0+bb) where vmask[b][t]==0  (pad-mask folded into K).
__global__ __launch_bounds__(256) void tr_bf16(const float* __restrict__ src,
        ushort* __restrict__ dst, int M, int N, const float* __restrict__ vm) {
    __shared__ ushort tl[64][65];
    const int bh = blockIdx.x;
    const int i0 = blockIdx.y*64, j0 = blockIdx.z*64;
    const float* s = src + (size_t)bh*M*N;
    ushort*      d = dst + (size_t)bh*M*N;
    const int tid = threadIdx.x;
    const int rr = tid>>4, c4 = (tid&15)*4;
    #pragma unroll
    for (int p=0;p<4;++p){
        int a = p*16+rr;
        float4 x = *reinterpret_cast<const float4*>(&s[(size_t)(i0+a)*N + j0 + c4]);
        tl[c4+0][a]=f2bu(x.x); tl[c4+1][a]=f2bu(x.y);
        tl[c4+2][a]=f2bu(x.z); tl[c4+3][a]=f2bu(x.w);
    }
    __syncthreads();
    #pragma unroll
    for (int p=0;p<4;++p){
        int bb = p*16+rr;
        ushort4 u;
        u.x=tl[bb][c4]; u.y=tl[bb][c4+1]; u.z=tl[bb][c4+2]; u.w=tl[bb][c4+3];
        if (vm && vm[(size_t)(bh>>4)*T_ + j0 + bb] == 0.f) { u.x=0;u.y=0;u.z=0;u.w=0; }
        *reinterpret_cast<ushort4*>(&d[(size_t)(j0+bb)*M + i0 + c4]) = u;
    }
}

// Swapped-operand flash attention: S^T = mfma(K, Q), softmax lane-local,
// P->bf16 via cvt_pk + permlane32_swap, O^T = mfma(V^T, P^T). No LDS.
__global__ __launch_bounds__(64, 2) void attn_fwd(
    const float* __restrict__ q, const float* __restrict__ fp,
    const float* __restrict__ hmask,
    const ushort* __restrict__ KT, const ushort* __restrict__ VT,
    float* __restrict__ out)
{
    const int bid = blockIdx.x;
    const int bh = bid & (BH-1);
    const int qb = (T_/QB - 1) - (bid >> 5);   // heavy-first
    const int i0 = qb*QB;
    const int lane = threadIdx.x & 63;
    const int col = lane & 31;                 // owned q-row (local)
    const int hi  = lane >> 5;

    const ushort* KTb = KT + (size_t)bh*T_*D_ + (size_t)col*D_ + hi*8;  // [T][D]
    const ushort* VTb = VT + (size_t)bh*T_*D_ + (size_t)col*T_ + hi*8;  // [D][T]

    const float hmv = hmask[(size_t)(bh>>4)*T_ + i0 + col];
    const float sscale = 1.4426950408889634f / fp[0];   // log2(e)/f folded into Q
    const float qs = (hmv != 0.f) ? sscale : 0.f;       // hmask==0 -> row scores all 0
    const float C1E10s = 1e-10f * 1.4426950408889634f;
    const float NINF = -__builtin_inff();

    // Q B-frags (pre-scaled): B[d = dc*16+hi*8+e][col]
    const float* qp = q + (size_t)bh*T_*D_ + (size_t)(i0+col)*D_ + hi*8;
    bf16x8 qf[4];
    #pragma unroll
    for (int dc=0; dc<4; ++dc){
        float4 x0 = *reinterpret_cast<const float4*>(qp + dc*16);
        float4 x1 = *reinterpret_cast<const float4*>(qp + dc*16 + 4);
        u32x4 dw;
        dw[0] = cvtpk(x0.x*qs, x0.y*qs);
        dw[1] = cvtpk(x0.z*qs, x0.w*qs);
        dw[2] = cvtpk(x1.x*qs, x1.y*qs);
        dw[3] = cvtpk(x1.z*qs, x1.w*qs);
        qf[dc] = __builtin_bit_cast(bf16x8, dw);
    }

    float m_run = NINF, l_run = 0.f;
    f32x16 o0, o1;
    #pragma unroll
    for (int r=0;r<16;++r){ o0[r]=0.f; o1[r]=0.f; }

    bf16x8 kf[8];
    auto ldK = [&](int j0v){
        #pragma unroll
        for (int kt=0;kt<2;++kt)
            #pragma unroll
            for (int dc=0;dc<4;++dc)
                kf[kt*4+dc] = *reinterpret_cast<const bf16x8*>(
                    KTb + (size_t)(j0v+kt*32)*D_ + dc*16);
    };
    ldK(0);

    const int nstep = ((i0 + QB - 1) >> 6) + 1;

    for (int t=0; t<nstep; ++t) {
        const int j0 = t*64;

        // S^T = K Q^T  (rows = keys, cols = q)
        f32x16 s0, s1;
        #pragma unroll
        for (int r=0;r<16;++r){ s0[r]=0.f; s1[r]=0.f; }
        #pragma unroll
        for (int dc=0;dc<4;++dc){
            s0 = __builtin_amdgcn_mfma_f32_32x32x16_bf16(kf[dc],   qf[dc], s0, 0,0,0);
            s1 = __builtin_amdgcn_mfma_f32_32x32x16_bf16(kf[4+dc], qf[dc], s1, 0,0,0);
        }

        // V A-frags for this tile (issue early; latency hides under softmax)
        bf16x8 vf[8];
        #pragma unroll
        for (int dt=0;dt<2;++dt)
            #pragma unroll
            for (int c2=0;c2<4;++c2)
                vf[dt*4+c2] = *reinterpret_cast<const bf16x8*>(
                    VTb + (size_t)dt*32*T_ + j0 + c2*16);

        // prefetch next K tile
        if (t+1 < nstep) ldK(j0+64);

        // masking: score==0 (K-row or Q-row zeroed) -> 1e-10; causal -> -inf
        if (j0 + 63 <= i0) {   // full tile, no causal work
            #pragma unroll
            for (int r=0;r<16;++r){
                float x0v = s0[r]; s0[r] = (x0v==0.f) ? C1E10s : x0v;
                float x1v = s1[r]; s1[r] = (x1v==0.f) ? C1E10s : x1v;
            }
        } else {
            const int th0 = i0 + col - j0 - 4*hi;
            const int th1 = th0 - 32;
            #pragma unroll
            for (int r=0;r<16;++r){
                const int base = (r&3) + 8*(r>>2);
                float x0v = s0[r]; x0v = (x0v==0.f) ? C1E10s : x0v;
                s0[r] = (base <= th0) ? x0v : NINF;
                float x1v = s1[r]; x1v = (x1v==0.f) ? C1E10s : x1v;
                s1[r] = (base <= th1) ? x1v : NINF;
            }
        }

        // online softmax (base-2 domain), one q-row per lane
        float mt = fmaxf(s0[0], s1[0]);
        #pragma unroll
        for (int r=1;r<16;++r) mt = fmaxf(mt, fmaxf(s0[r], s1[r]));
        mt = fmaxf(mt, __shfl_xor(mt, 32));
        const float mn = fmaxf(m_run, mt);
        const float fac = __builtin_amdgcn_exp2f(m_run - mn);
        m_run = mn;
        float rs = 0.f;
        #pragma unroll
        for (int r=0;r<16;++r){
            float p0 = __builtin_amdgcn_exp2f(s0[r] - mn);
            float p1 = __builtin_amdgcn_exp2f(s1[r] - mn);
            s0[r]=p0; s1[r]=p1; rs += p0 + p1;
        }
        rs += __shfl_xor(rs, 32);
        l_run = l_run*fac + rs;
        #pragma unroll
        for (int r=0;r<16;++r){ o0[r]*=fac; o1[r]*=fac; }

        // P -> bf16 B-frags: 4 cvt_pk + 2 permlane32_swap per 16-key chunk
        bf16x8 pb[4];
        #pragma unroll
        for (int c2=0;c2<4;++c2){
            const f32x16& ps = (c2<2) ? s0 : s1;
            const int rb = (c2&1)*8;
            u32 a0 = cvtpk(ps[rb+0], ps[rb+1]);
            u32 a1 = cvtpk(ps[rb+2], ps[rb+3]);
            u32 a2 = cvtpk(ps[rb+4], ps[rb+5]);
            u32 a3 = cvtpk(ps[rb+6], ps[rb+7]);
            asm("v_permlane32_swap_b32 %0, %1" : "+v"(a0), "+v"(a2));
            asm("v_permlane32_swap_b32 %0, %1" : "+v"(a1), "+v"(a3));
            u32x4 dw; dw[0]=a0; dw[1]=a1; dw[2]=a2; dw[3]=a3;
            pb[c2] = __builtin_bit_cast(bf16x8, dw);
        }

        // O^T += V^T P^T
        #pragma unroll
        for (int c2=0;c2<4;++c2){
            o0 = __builtin_amdgcn_mfma_f32_32x32x16_bf16(vf[c2],   pb[c2], o0, 0,0,0);
            o1 = __builtin_amdgcn_mfma_f32_32x32x16_bf16(vf[4+c2], pb[c2], o1, 0,0,0);
        }
    }

    // epilogue: O = O^T / l, scatter back to [q][d]
    const float rinv = 1.0f / l_run;
    float* op = out + (size_t)bh*T_*D_ + (size_t)(i0+col)*D_;
    #pragma unroll
    for (int r=0;r<16;++r){
        const int dd = (r&3) + 8*(r>>2) + 4*hi;
        op[dd]    = o0[r]*rinv;
        op[32+dd] = o1[r]*rinv;
    }
}

extern "C" void kernel_launch(void* const* d_in, const int* in_sizes, int n_in,
                              void* d_out, int out_size, void* d_ws, size_t ws_size,
                              hipStream_t stream) {
    const float* q  = (const float*)d_in[0];
    const float* k  = (const float*)d_in[1];
    const float* v  = (const float*)d_in[2];
    const float* f  = (const float*)d_in[3];
    const float* vm = (const float*)d_in[4];
    const float* hm = (const float*)d_in[5];
    float* out = (float*)d_out;

    const size_t slab = (size_t)BH * T_ * D_;
    ushort* KT = (ushort*)d_ws;
    ushort* VT = KT + slab;
    // ws requirement identical to round 2 (proven sufficient): 2 bf16 slabs.

    // k: f32 [D][T] -> KT bf16 [T][D], vmask'd rows zeroed
    hipLaunchKernelGGL(tr_bf16, dim3(BH, 1, T_/64), dim3(256), 0, stream,
                       k, KT, D_, T_, vm);
    // v: f32 [T][D] -> VT bf16 [D][T]
    hipLaunchKernelGGL(tr_bf16, dim3(BH, T_/64, 1), dim3(256), 0, stream,
                       v, VT, T_, D_, (const float*)nullptr);

    dim3 grid(BH * (T_/QB));   // 2048 one-wave blocks
    dim3 block(64);
    hipLaunchKernelGGL(attn_fwd, grid, block, 0, stream, q, f, hm, KT, VT, out);
}